// Round 9
// baseline (675.499 us; speedup 1.0000x reference)
//
#include <hip/hip_runtime.h>

typedef unsigned short u16;
typedef unsigned int   u32;
typedef __attribute__((ext_vector_type(8))) short short8;
typedef __attribute__((ext_vector_type(4))) float f32x4;
typedef __attribute__((ext_vector_type(2))) float f32x2;
typedef __attribute__((ext_vector_type(4))) u32   u32x4;
typedef __attribute__((ext_vector_type(2))) u32   u32x2;

#define MFMA16 __builtin_amdgcn_mfma_f32_16x16x32_bf16

// W pre-split storage: [0,524288) hi of [Wf;Wg]; [524288,1048576) lo; [1048576,1310720) rne(Wh)
__device__ u16 Wsplit[1310720];

__device__ __forceinline__ u16 f2bf(float f) {           // rne
  u32 u = __float_as_uint(f);
  return (u16)((u + 0x7FFFu + ((u >> 16) & 1u)) >> 16);
}
__device__ __forceinline__ u32 cvtpk(float a, float b) { // packed rne {bf16(a),bf16(b)}
  u32 d; asm("v_cvt_pk_bf16_f32 %0, %1, %2" : "=v"(d) : "v"(a), "v"(b)); return d;
}
__device__ __forceinline__ void split2(float a, float b, u32& hi, u32& lo) {
  u32 ua = __float_as_uint(a), ub = __float_as_uint(b);
  hi = __builtin_amdgcn_perm(ub, ua, 0x07060302u);       // {trunc(a), trunc(b)}
  lo = cvtpk(a - __uint_as_float(ua & 0xFFFF0000u), b - __uint_as_float(ub & 0xFFFF0000u));
}
__device__ __forceinline__ void gload16(const void* g, void* l) {
  __builtin_amdgcn_global_load_lds(
      (const __attribute__((address_space(1))) void*)g,
      (__attribute__((address_space(3))) void*)l, 16, 0, 0);
}

// ---------------------------------------------------------------------------
// prep_w: split weights into bf16 hi/lo (runs once per call, trivial cost)
// ---------------------------------------------------------------------------
__global__ __launch_bounds__(256)
void prep_w(const float* __restrict__ Wf, const float* __restrict__ Wg,
            const float* __restrict__ Wh)
{
  const int r = blockIdx.x;                    // 0..1535
  const int k = threadIdx.x * 2;
  const float* src = (r < 512) ? (Wf + (size_t)r * 512)
                   : (r < 1024) ? (Wg + (size_t)(r - 512) * 512)
                                : (Wh + (size_t)(r - 1024) * 512);
  f32x2 v = *(const f32x2*)(src + k);
  if (r < 1024) {
    u32 hi, lo; split2(v[0], v[1], hi, lo);
    *(u32*)(Wsplit + (size_t)r * 512 + k) = hi;
    *(u32*)(Wsplit + 524288 + (size_t)r * 512 + k) = lo;
  } else {
    *(u32*)(Wsplit + 1048576 + (size_t)(r - 1024) * 512 + k) = cvtpk(v[0], v[1]);
  }
}

// ---------------------------------------------------------------------------
// prep_x: x[512][65536] fp32 -> xT[65536][512] bf16 hi(trunc)/lo(rne).
// ---------------------------------------------------------------------------
__global__ __launch_bounds__(256)
void prep_x(const float* __restrict__ x, u16* __restrict__ xhi, u16* __restrict__ xlo)
{
  __shared__ float tile[64 * 256];             // 64 KB, pitch 256 (conflict-free)
  const int bk = blockIdx.x & 7, bn = blockIdx.x >> 3;
  const int t = threadIdx.x;
  const int cw = (t & 63) * 4, r0 = (t >> 6) * 16;
#pragma unroll
  for (int it = 0; it < 16; ++it) {
    const int r = r0 + it;
    *(f32x4*)&tile[r * 256 + cw] =
        *(const f32x4*)(x + (size_t)(bk * 64 + r) * 65536 + (size_t)bn * 256 + cw);
  }
  __syncthreads();
  u32 hi[32], lo[32];
#pragma unroll
  for (int q = 0; q < 32; ++q)
    split2(tile[(2 * q) * 256 + t], tile[(2 * q + 1) * 256 + t], hi[q], lo[q]);
  const size_t ob = (size_t)(bn * 256 + t) * 512 + bk * 64;
#pragma unroll
  for (int c4 = 0; c4 < 8; ++c4) {
    *(u32x4*)(xhi + ob + c4 * 8) = (u32x4){hi[4*c4], hi[4*c4+1], hi[4*c4+2], hi[4*c4+3]};
    *(u32x4*)(xlo + ob + c4 * 8) = (u32x4){lo[4*c4], lo[4*c4+1], lo[4*c4+2], lo[4*c4+3]};
  }
}

// ---------------------------------------------------------------------------
// conv_fg: EMU bf16-pair GEMM, m97 multi-block structure. M=1024 (tm 0-3 = f,
// tm 4-7 = g via sigma rows), 128x128 tile, BK=32, 256 thr / 4 waves (2x2).
// LDS single-buffered 32 KB (Ah/Al/Bh/Bl x 8 KB, linear, DMA-written).
// Source k-slot swizzle (involution, (row>>1)&3) -> 2-way-free ds_reads.
// Plain __syncthreads 2-barrier loop; occupancy (3-4 blocks/CU) provides the
// overlap (m97: 912 TF with this exact recipe at 3 blocks/CU).
// ---------------------------------------------------------------------------
__global__ __launch_bounds__(256)
void conv_fg(const u16* __restrict__ xhi, const u16* __restrict__ xlo,
             u16* __restrict__ fhi, u16* __restrict__ flo,
             u16* __restrict__ gThi, u16* __restrict__ gTlo)
{
  __shared__ u16 sAh[4096], sAl[4096], sBh[4096], sBl[4096]; // 8 KB each
  const int bid = blockIdx.x;
  const int xcd = bid & 7, idx = bid >> 3;      // 4096 = 8 XCD x (64 tn x 8 tm)
  const int tn = xcd * 64 + (idx >> 3);
  const int tm = idx & 7;                       // stripe-inner: same-tn adjacent
  const bool gmode = tm >= 4;
  const int t = threadIdx.x, lane = t & 63, wid = t >> 6;
  const int wr = wid >> 1, wc = wid & 1, lr = lane & 15, lq = lane >> 4;

  // staging chunks: gload q covers LDS bytes [q*4096 + t*16); chunk e = q*256+t
  // -> (row = e>>2, slot = e&3); global k = ((slot ^ ((row>>1)&3)) << 3).
  const int row0 = t >> 2, row1 = 64 + (t >> 2);
  const int ks0 = (((t & 3) ^ ((row0 >> 1) & 3)) << 3);
  const int ks1 = (((t & 3) ^ ((row1 >> 1) & 3)) << 3);
  const int arA0 = tm * 128 + row0, arA1 = tm * 128 + row1;
  const int bxr0 = gmode ? ((((tn & 1) << 7) + row0) * 256 + (tn >> 1)) : (tn * 128 + row0);
  const int bxr1 = gmode ? ((((tn & 1) << 7) + row1) * 256 + (tn >> 1)) : (tn * 128 + row1);

  // fragment read offsets (u16 units), matching read-side XOR
  int offA[4], offB[4];
#pragma unroll
  for (int mi = 0; mi < 4; ++mi) {
    const int rowA = wr * 64 + mi * 16 + lr;
    offA[mi] = rowA * 32 + ((lq ^ ((rowA >> 1) & 3)) << 3);
  }
#pragma unroll
  for (int ni = 0; ni < 4; ++ni) {
    const int rowB = wc * 64 + ni * 16 + lr;
    offB[ni] = rowB * 32 + ((lq ^ ((rowB >> 1) & 3)) << 3);
  }

  f32x4 acc[4][4] = {};

  for (int k0 = 0; k0 < 512; k0 += 32) {
    gload16(Wsplit + (size_t)arA0 * 512 + k0 + ks0,          (char*)sAh + t * 16);
    gload16(Wsplit + (size_t)arA1 * 512 + k0 + ks1,          (char*)sAh + 4096 + t * 16);
    gload16(Wsplit + 524288 + (size_t)arA0 * 512 + k0 + ks0, (char*)sAl + t * 16);
    gload16(Wsplit + 524288 + (size_t)arA1 * 512 + k0 + ks1, (char*)sAl + 4096 + t * 16);
    gload16(xhi + (size_t)bxr0 * 512 + k0 + ks0,             (char*)sBh + t * 16);
    gload16(xhi + (size_t)bxr1 * 512 + k0 + ks1,             (char*)sBh + 4096 + t * 16);
    gload16(xlo + (size_t)bxr0 * 512 + k0 + ks0,             (char*)sBl + t * 16);
    gload16(xlo + (size_t)bxr1 * 512 + k0 + ks1,             (char*)sBl + 4096 + t * 16);
    __syncthreads();
    short8 ah[4], bh[4], bl[4];
#pragma unroll
    for (int mi = 0; mi < 4; ++mi) ah[mi] = *(const short8*)(sAh + offA[mi]);
#pragma unroll
    for (int ni = 0; ni < 4; ++ni) {
      bh[ni] = *(const short8*)(sBh + offB[ni]);
      bl[ni] = *(const short8*)(sBl + offB[ni]);
    }
#pragma unroll
    for (int mi = 0; mi < 4; ++mi)
#pragma unroll
      for (int ni = 0; ni < 4; ++ni) {
        acc[mi][ni] = MFMA16(ah[mi], bh[ni], acc[mi][ni], 0, 0, 0);
        acc[mi][ni] = MFMA16(ah[mi], bl[ni], acc[mi][ni], 0, 0, 0);
      }
    short8 al[4];
#pragma unroll
    for (int mi = 0; mi < 4; ++mi) al[mi] = *(const short8*)(sAl + offA[mi]);
#pragma unroll
    for (int mi = 0; mi < 4; ++mi)
#pragma unroll
      for (int ni = 0; ni < 4; ++ni)
        acc[mi][ni] = MFMA16(al[mi], bh[ni], acc[mi][ni], 0, 0, 0);
    __syncthreads();
  }

  const int cch = (gmode ? (tm - 4) : tm) * 128 + wr * 64;
  const int cbase = tn * 128 + wc * 64;
  u16* dsthi = gmode ? gThi : fhi;
  u16* dstlo = gmode ? gTlo : flo;
#pragma unroll
  for (int mi = 0; mi < 4; ++mi)
#pragma unroll
    for (int ni = 0; ni < 4; ++ni) {
      const int r0 = cch + mi * 16 + lq * 4;
      const int cc = cbase + ni * 16 + lr;
#pragma unroll
      for (int r = 0; r < 4; ++r) {
        float val = acc[mi][ni][r];
        u32 u = __float_as_uint(val);
        const size_t o = (size_t)(r0 + r) * 65536 + cc;
        dsthi[o] = (u16)(u >> 16);
        dstlo[o] = f2bf(val - __uint_as_float(u & 0xFFFF0000u));
      }
    }
}

// ---------------------------------------------------------------------------
// conv_h: plain bf16 GEMM h = rne(Wh) @ x, all-gload staging, out bf16.
// ---------------------------------------------------------------------------
__global__ __launch_bounds__(256)
void conv_h(const u16* __restrict__ xhi, u16* __restrict__ hb)
{
  __shared__ u16 sA[128 * 32], sB[128 * 32];
  const int bid = blockIdx.x;
  const int xcd = bid & 7, idx = bid >> 3;      // 2048 = 8 x (64 tn x 4 tm)
  const int tn = xcd * 64 + (idx >> 2);
  const int tm = idx & 3;
  const int t = threadIdx.x, lane = t & 63, wid = t >> 6;
  const int wr = wid >> 1, wc = wid & 1, lr = lane & 15, lq = lane >> 4;
  const int grl = t >> 2, gko = t & 3;
  const int ldsb = wid * 1024;

  f32x4 acc[4][4] = {};

  for (int k0 = 0; k0 < 512; k0 += 32) {
#pragma unroll
    for (int q = 0; q < 2; ++q) {
      const int row = q * 64 + grl;
      const size_t ao = (size_t)1048576 + (size_t)(tm * 128 + row) * 512 + k0 + gko * 8;
      gload16(Wsplit + ao, (char*)sA + q * 4096 + ldsb);
      const size_t bo = (size_t)(tn * 128 + row) * 512 + k0 + gko * 8;
      gload16(xhi + bo, (char*)sB + q * 4096 + ldsb);
    }
    __syncthreads();
    short8 af[4], bfr[4];
#pragma unroll
    for (int mi = 0; mi < 4; ++mi)
      af[mi] = *(const short8*)(sA + (wr * 64 + mi * 16 + lr) * 32 + lq * 8);
#pragma unroll
    for (int ni = 0; ni < 4; ++ni)
      bfr[ni] = *(const short8*)(sB + (wc * 64 + ni * 16 + lr) * 32 + lq * 8);
#pragma unroll
    for (int mi = 0; mi < 4; ++mi)
#pragma unroll
      for (int ni = 0; ni < 4; ++ni)
        acc[mi][ni] = MFMA16(af[mi], bfr[ni], acc[mi][ni], 0, 0, 0);
    __syncthreads();
  }
  const int rb = tm * 128 + wr * 64, cbase = tn * 128 + wc * 64;
#pragma unroll
  for (int mi = 0; mi < 4; ++mi)
#pragma unroll
    for (int ni = 0; ni < 4; ++ni) {
      const int r0 = rb + mi * 16 + lq * 4, cc = cbase + ni * 16 + lr;
#pragma unroll
      for (int r = 0; r < 4; ++r)
        hb[(size_t)(r0 + r) * 65536 + cc] = f2bf(acc[mi][ni][r]);
    }
}

// ---------------------------------------------------------------------------
// scores: per (c, jt): S-tile = f[c](256 x K) @ gT[c][jt](128 x K)^T, EMU.
// Block owns FULL softmax columns (256 rows in-block) -> normalized
// PT[c][j][i] bf16. 8 waves (4M x 2N), 48 KB single-buffered staging,
// __launch_bounds__(512,4) -> 2 blocks/CU.
// ---------------------------------------------------------------------------
__global__ __launch_bounds__(512, 4)
void scores_kernel(const u16* __restrict__ fhi, const u16* __restrict__ flo,
                   const u16* __restrict__ gThi, const u16* __restrict__ gTlo,
                   u16* __restrict__ Pt)
{
  __shared__ u16 sAh[8192], sAl[8192];          // 16 KB each (256 rows x 32 k)
  __shared__ u16 sBh[4096], sBl[4096];          // 8 KB each (128 rows x 32 k)
  float* cmax = (float*)sAh;                    // aliases staging (dead after K)
  float* csum = (float*)(sAh + 2048);           // byte offset 4096
  const int bid = blockIdx.x;
  const int xcd = bid & 7, i2 = bid >> 3;       // 1024 = 8 x (64 c x 2 jt)
  const int c = xcd * 64 + (i2 >> 1), jt = i2 & 1;
  const size_t cb = (size_t)c * 65536;
  const int t = threadIdx.x, lane = t & 63, wid = t >> 6;
  const int wr = wid >> 1, wc = wid & 1, lr = lane & 15, lq = lane >> 4;

  // A chunks: e = q*512 + t (q=0,1) -> row = e>>2 (0..255), slot = e&3
  const int arow0 = t >> 2, arow1 = 128 + (t >> 2);
  const int aks0 = (((t & 3) ^ ((arow0 >> 1) & 3)) << 3);
  const int aks1 = (((t & 3) ^ ((arow1 >> 1) & 3)) << 3);
  // B chunks: e = t -> row = t>>2 (0..127)
  const int brow = t >> 2;
  const int bks  = (((t & 3) ^ ((brow >> 1) & 3)) << 3);

  int offA[4], offB[4];
#pragma unroll
  for (int mi = 0; mi < 4; ++mi) {
    const int rowA = wr * 64 + mi * 16 + lr;    // 0..255
    offA[mi] = rowA * 32 + ((lq ^ ((rowA >> 1) & 3)) << 3);
  }
#pragma unroll
  for (int ni = 0; ni < 4; ++ni) {
    const int rowB = wc * 64 + ni * 16 + lr;    // 0..127
    offB[ni] = rowB * 32 + ((lq ^ ((rowB >> 1) & 3)) << 3);
  }

  f32x4 acc[4][4] = {};

  for (int k0 = 0; k0 < 256; k0 += 32) {
    gload16(fhi + cb + (size_t)arow0 * 256 + k0 + aks0, (char*)sAh + t * 16);
    gload16(fhi + cb + (size_t)arow1 * 256 + k0 + aks1, (char*)sAh + 8192 + t * 16);
    gload16(flo + cb + (size_t)arow0 * 256 + k0 + aks0, (char*)sAl + t * 16);
    gload16(flo + cb + (size_t)arow1 * 256 + k0 + aks1, (char*)sAl + 8192 + t * 16);
    gload16(gThi + cb + (size_t)(jt * 128 + brow) * 256 + k0 + bks, (char*)sBh + t * 16);
    gload16(gTlo + cb + (size_t)(jt * 128 + brow) * 256 + k0 + bks, (char*)sBl + t * 16);
    __syncthreads();
    short8 ah[4], bh[4], bl[4];
#pragma unroll
    for (int mi = 0; mi < 4; ++mi) ah[mi] = *(const short8*)(sAh + offA[mi]);
#pragma unroll
    for (int ni = 0; ni < 4; ++ni) {
      bh[ni] = *(const short8*)(sBh + offB[ni]);
      bl[ni] = *(const short8*)(sBl + offB[ni]);
    }
#pragma unroll
    for (int mi = 0; mi < 4; ++mi)
#pragma unroll
      for (int ni = 0; ni < 4; ++ni) {
        acc[mi][ni] = MFMA16(ah[mi], bh[ni], acc[mi][ni], 0, 0, 0);
        acc[mi][ni] = MFMA16(ah[mi], bl[ni], acc[mi][ni], 0, 0, 0);
      }
    short8 al[4];
#pragma unroll
    for (int mi = 0; mi < 4; ++mi) al[mi] = *(const short8*)(sAl + offA[mi]);
#pragma unroll
    for (int mi = 0; mi < 4; ++mi)
#pragma unroll
      for (int ni = 0; ni < 4; ++ni)
        acc[mi][ni] = MFMA16(al[mi], bh[ni], acc[mi][ni], 0, 0, 0);
    __syncthreads();
  }

  // ---- full-column softmax over i (rows span wr,mi,lq,r), per column j
#pragma unroll
  for (int ni = 0; ni < 4; ++ni) {
    const int col = wc * 64 + ni * 16 + lr;
    float m = -3.4e38f;
#pragma unroll
    for (int mi = 0; mi < 4; ++mi) {
      f32x4 a = acc[mi][ni];
      m = fmaxf(m, fmaxf(fmaxf(a[0], a[1]), fmaxf(a[2], a[3])));
    }
    m = fmaxf(m, __shfl_xor(m, 16));
    m = fmaxf(m, __shfl_xor(m, 32));
    cmax[wr * 128 + col] = m;
  }
  __syncthreads();
#pragma unroll
  for (int ni = 0; ni < 4; ++ni) {
    const int col = wc * 64 + ni * 16 + lr;
    const float M = fmaxf(fmaxf(cmax[col], cmax[128 + col]),
                          fmaxf(cmax[256 + col], cmax[384 + col]));
    float s = 0.f;
#pragma unroll
    for (int mi = 0; mi < 4; ++mi)
#pragma unroll
      for (int r = 0; r < 4; ++r) {
        float e = __expf(acc[mi][ni][r] - M);
        acc[mi][ni][r] = e; s += e;
      }
    s += __shfl_xor(s, 16);
    s += __shfl_xor(s, 32);
    csum[wr * 128 + col] = s;
  }
  __syncthreads();
#pragma unroll
  for (int ni = 0; ni < 4; ++ni) {
    const int col = wc * 64 + ni * 16 + lr;
    const float rs = 1.f / (csum[col] + csum[128 + col] + csum[256 + col] + csum[384 + col]);
    const int j = jt * 128 + col;
#pragma unroll
    for (int mi = 0; mi < 4; ++mi) {
      u32 w0 = cvtpk(acc[mi][ni][0] * rs, acc[mi][ni][1] * rs);
      u32 w1 = cvtpk(acc[mi][ni][2] * rs, acc[mi][ni][3] * rs);
      *(u32x2*)(Pt + cb + (size_t)j * 256 + wr * 64 + mi * 16 + lq * 4) = (u32x2){w0, w1};
    }
  }
}

// ---------------------------------------------------------------------------
// attn: out[c,i,j] = x[c,i,j] + sum_k h[c,i,k] * PT[c,j,k]. Plain bf16.
// ---------------------------------------------------------------------------
__global__ __launch_bounds__(256)
void attn_kernel(const u16* __restrict__ hb, const u16* __restrict__ Pt,
                 const float* __restrict__ x, float* __restrict__ out)
{
  __shared__ u16 sA[128 * 32], sB[128 * 32];
  const int bid = blockIdx.x;
  const int wg = (bid & 7) * 256 + (bid >> 3);
  const int c = wg >> 2, tm = (wg >> 1) & 1, tn = wg & 1;
  const int t = threadIdx.x, lane = t & 63, wid = t >> 6;
  const int wr = wid >> 1, wc = wid & 1, lr = lane & 15, lq = lane >> 4;
  const size_t cb = (size_t)c * 65536;
  const int grl = t >> 2, gko = t & 3;
  const int ldsb = wid * 1024;

  f32x4 acc[4][4] = {};

  for (int k0 = 0; k0 < 256; k0 += 32) {
#pragma unroll
    for (int q = 0; q < 2; ++q) {
      const int row = q * 64 + grl;
      gload16(hb + cb + (size_t)(tm * 128 + row) * 256 + k0 + gko * 8,
              (char*)sA + q * 4096 + ldsb);
      gload16(Pt + cb + (size_t)(tn * 128 + row) * 256 + k0 + gko * 8,
              (char*)sB + q * 4096 + ldsb);
    }
    __syncthreads();
    short8 af[4], bfr[4];
#pragma unroll
    for (int mi = 0; mi < 4; ++mi)
      af[mi] = *(const short8*)(sA + (wr * 64 + mi * 16 + lr) * 32 + lq * 8);
#pragma unroll
    for (int ni = 0; ni < 4; ++ni)
      bfr[ni] = *(const short8*)(sB + (wc * 64 + ni * 16 + lr) * 32 + lq * 8);
#pragma unroll
    for (int mi = 0; mi < 4; ++mi)
#pragma unroll
      for (int ni = 0; ni < 4; ++ni)
        acc[mi][ni] = MFMA16(af[mi], bfr[ni], acc[mi][ni], 0, 0, 0);
    __syncthreads();
  }

  const float* Xc = x + cb;
  float* Oc = out + cb;
  const int rb = tm * 128 + wr * 64, cbase = tn * 128 + wc * 64;
#pragma unroll
  for (int mi = 0; mi < 4; ++mi)
#pragma unroll
    for (int ni = 0; ni < 4; ++ni) {
      const int r0 = rb + mi * 16 + lq * 4, cc = cbase + ni * 16 + lr;
#pragma unroll
      for (int r = 0; r < 4; ++r) {
        const size_t idx = (size_t)(r0 + r) * 256 + cc;
        Oc[idx] = Xc[idx] + acc[mi][ni][r];
      }
    }
}

// ---------------------------------------------------------------------------
extern "C" void kernel_launch(void* const* d_in, const int* in_sizes, int n_in,
                              void* d_out, int out_size, void* d_ws, size_t ws_size,
                              hipStream_t stream)
{
  (void)in_sizes; (void)n_in; (void)out_size; (void)ws_size;
  const float* x  = (const float*)d_in[0];
  const float* Wf = (const float*)d_in[1];
  const float* Wg = (const float*)d_in[2];
  const float* Wh = (const float*)d_in[3];
  float* out = (float*)d_out;
  char*  ws  = (char*)d_ws;

  // ws (256 MiB): [xhi 64][xlo 64][gThi 64][gTlo 64]; d_out hosts f hi/lo.
  u16* xhi  = (u16*)ws;
  u16* xlo  = (u16*)(ws + 67108864);
  u16* gThi = (u16*)(ws + 134217728);
  u16* gTlo = (u16*)(ws + 201326592);
  u16* fhi  = (u16*)d_out;
  u16* flo  = (u16*)d_out + 33554432;
  u16* hb   = xlo;   // h overwrites xlo after conv_fg
  u16* Pt   = xhi;   // PT overwrites xhi after conv_h

  dim3 blk(256, 1, 1);
  prep_w       <<<dim3(1536, 1, 1), blk, 0, stream>>>(Wf, Wg, Wh);
  prep_x       <<<dim3(2048, 1, 1), blk, 0, stream>>>(x, xhi, xlo);
  conv_fg      <<<dim3(4096, 1, 1), blk, 0, stream>>>(xhi, xlo, fhi, flo, gThi, gTlo);
  conv_h       <<<dim3(2048, 1, 1), blk, 0, stream>>>(xhi, hb);
  scores_kernel<<<dim3(1024, 1, 1), dim3(512, 1, 1), 0, stream>>>(fhi, flo, gThi, gTlo, Pt);
  attn_kernel  <<<dim3(2048, 1, 1), blk, 0, stream>>>(hb, Pt, x, out);
}

// Round 10
// 414.384 us; speedup vs baseline: 1.6301x; 1.6301x over previous
//
#include <hip/hip_runtime.h>

typedef unsigned short u16;
typedef unsigned int   u32;
typedef __attribute__((ext_vector_type(8))) _Float16 half8;
typedef __attribute__((ext_vector_type(4))) float f32x4;
typedef __attribute__((ext_vector_type(2))) float f32x2;
typedef __attribute__((ext_vector_type(4))) u32   u32x4;
typedef __attribute__((ext_vector_type(4))) unsigned short u16x4;

#define MFMAH __builtin_amdgcn_mfma_f32_16x16x32_f16

// W fp16 storage: rows 0-511 = Wf, 512-1023 = Wg, 1024-1535 = Wh, k-contig.
__device__ u16 W16[786432];

__device__ __forceinline__ u16 f2h(float f) {            // fp32 -> fp16 rne
  _Float16 h = (_Float16)f;
  union { _Float16 hh; u16 u; } cv; cv.hh = h; return cv.u;
}
__device__ __forceinline__ u32 pkh(float a, float b) {   // two rne halves packed
  return (u32)f2h(a) | ((u32)f2h(b) << 16);
}
__device__ __forceinline__ void gload16(const void* g, void* l) {
  __builtin_amdgcn_global_load_lds(
      (const __attribute__((address_space(1))) void*)g,
      (__attribute__((address_space(3))) void*)l, 16, 0, 0);
}

// ---------------------------------------------------------------------------
// prep_w: W fp32 -> fp16 (rne)
// ---------------------------------------------------------------------------
__global__ __launch_bounds__(256)
void prep_w(const float* __restrict__ Wf, const float* __restrict__ Wg,
            const float* __restrict__ Wh)
{
  const int r = blockIdx.x;                    // 0..1535
  const int k = threadIdx.x * 2;
  const float* src = (r < 512) ? (Wf + (size_t)r * 512)
                   : (r < 1024) ? (Wg + (size_t)(r - 512) * 512)
                                : (Wh + (size_t)(r - 1024) * 512);
  f32x2 v = *(const f32x2*)(src + k);
  *(u32*)(W16 + (size_t)r * 512 + k) = pkh(v[0], v[1]);
}

// ---------------------------------------------------------------------------
// prep_x: x[512][65536] fp32 -> xT[65536][512] fp16 (rne).
// ---------------------------------------------------------------------------
__global__ __launch_bounds__(256)
void prep_x(const float* __restrict__ x, u16* __restrict__ x16)
{
  __shared__ float tile[64 * 256];             // 64 KB
  const int bk = blockIdx.x & 7, bn = blockIdx.x >> 3;
  const int t = threadIdx.x;
  const int cw = (t & 63) * 4, r0 = (t >> 6) * 16;
#pragma unroll
  for (int it = 0; it < 16; ++it) {
    const int r = r0 + it;
    *(f32x4*)&tile[r * 256 + cw] =
        *(const f32x4*)(x + (size_t)(bk * 64 + r) * 65536 + (size_t)bn * 256 + cw);
  }
  __syncthreads();
  u32 w[32];
#pragma unroll
  for (int q = 0; q < 32; ++q)
    w[q] = pkh(tile[(2 * q) * 256 + t], tile[(2 * q + 1) * 256 + t]);
  const size_t ob = (size_t)(bn * 256 + t) * 512 + bk * 64;
#pragma unroll
  for (int c4 = 0; c4 < 8; ++c4)
    *(u32x4*)(x16 + ob + c4 * 8) = (u32x4){w[4*c4], w[4*c4+1], w[4*c4+2], w[4*c4+3]};
}

// ---------------------------------------------------------------------------
// conv_fgh: fused fp16 GEMM, M=1536 ([f;g;h] = [Wf;Wg;Wh] @ x).
// tm 0-3: f (direct rows), tm 4-7: g via sigma rows -> writes gT[c][j][k],
// tm 8-11: h (direct rows). 128x128 tile, BK=32, 256 thr / 4 waves (2x2).
// All staging via global_load_lds, k-slot source swizzle (2-way-free reads).
// XCD-chunked stripe-inner grid: B-tile reused by 12 adjacent tm on one XCD.
// ---------------------------------------------------------------------------
__global__ __launch_bounds__(256)
void conv_fgh(const u16* __restrict__ x16, u16* __restrict__ fb,
              u16* __restrict__ gTb, u16* __restrict__ hb)
{
  __shared__ u16 sA[4096], sB[4096];           // 8 KB each
  const int bid = blockIdx.x;
  const int xcd = bid & 7, idx = bid >> 3;     // 6144 = 8 XCD x (64 tn x 12 tm)
  const int tn = xcd * 64 + idx / 12;
  const int tm = idx % 12;
  const bool gmode = (tm >= 4) && (tm < 8);
  const int t = threadIdx.x, lane = t & 63, wid = t >> 6;
  const int wr = wid >> 1, wc = wid & 1, lr = lane & 15, lq = lane >> 4;

  const int row0 = t >> 2, row1 = 64 + (t >> 2);
  const int ks0 = (((t & 3) ^ ((row0 >> 1) & 3)) << 3);
  const int ks1 = (((t & 3) ^ ((row1 >> 1) & 3)) << 3);
  const int arA0 = tm * 128 + row0, arA1 = tm * 128 + row1;
  const int bxr0 = gmode ? ((((tn & 1) << 7) + row0) * 256 + (tn >> 1)) : (tn * 128 + row0);
  const int bxr1 = gmode ? ((((tn & 1) << 7) + row1) * 256 + (tn >> 1)) : (tn * 128 + row1);

  int offA[4], offB[4];
#pragma unroll
  for (int mi = 0; mi < 4; ++mi) {
    const int rowA = wr * 64 + mi * 16 + lr;
    offA[mi] = rowA * 32 + ((lq ^ ((rowA >> 1) & 3)) << 3);
  }
#pragma unroll
  for (int ni = 0; ni < 4; ++ni) {
    const int rowB = wc * 64 + ni * 16 + lr;
    offB[ni] = rowB * 32 + ((lq ^ ((rowB >> 1) & 3)) << 3);
  }

  f32x4 acc[4][4] = {};

  for (int k0 = 0; k0 < 512; k0 += 32) {
    gload16(W16 + (size_t)arA0 * 512 + k0 + ks0, (char*)sA + t * 16);
    gload16(W16 + (size_t)arA1 * 512 + k0 + ks1, (char*)sA + 4096 + t * 16);
    gload16(x16 + (size_t)bxr0 * 512 + k0 + ks0, (char*)sB + t * 16);
    gload16(x16 + (size_t)bxr1 * 512 + k0 + ks1, (char*)sB + 4096 + t * 16);
    __syncthreads();
    half8 a[4], b[4];
#pragma unroll
    for (int mi = 0; mi < 4; ++mi) a[mi] = *(const half8*)(sA + offA[mi]);
#pragma unroll
    for (int ni = 0; ni < 4; ++ni) b[ni] = *(const half8*)(sB + offB[ni]);
#pragma unroll
    for (int mi = 0; mi < 4; ++mi)
#pragma unroll
      for (int ni = 0; ni < 4; ++ni)
        acc[mi][ni] = MFMAH(a[mi], b[ni], acc[mi][ni], 0, 0, 0);
    __syncthreads();
  }

  u16* dst = gmode ? gTb : ((tm < 4) ? fb : hb);
  const int mloc = (tm < 4) ? tm : (gmode ? (tm - 4) : (tm - 8));
  const int rbase = mloc * 128 + wr * 64;
  const int cbase = tn * 128 + wc * 64;
#pragma unroll
  for (int mi = 0; mi < 4; ++mi)
#pragma unroll
    for (int ni = 0; ni < 4; ++ni) {
      const int r0 = rbase + mi * 16 + lq * 4;
      const int cc = cbase + ni * 16 + lr;
#pragma unroll
      for (int r = 0; r < 4; ++r)
        dst[(size_t)(r0 + r) * 65536 + cc] = f2h(acc[mi][ni][r]);
    }
}

// ---------------------------------------------------------------------------
// scores: per (c, jt): S = f[c](256 x 256) @ gT[c][jt](128 x 256)^T, fp16.
// Block owns FULL softmax columns -> writes normalized PT[c][j][i] fp16.
// 512 thr / 8 waves (4M x 2N).
// ---------------------------------------------------------------------------
__global__ __launch_bounds__(512)
void scores_kernel(const u16* __restrict__ fb, const u16* __restrict__ gTb,
                   u16* __restrict__ Pt)
{
  __shared__ u16 sA[8192];                     // 16 KB: 256 rows x 32 k
  __shared__ u16 sB[4096];                     // 8 KB: 128 rows x 32 k
  __shared__ float cmax[512], csum[512];
  const int bid = blockIdx.x;
  const int xcd = bid & 7, i2 = bid >> 3;      // 1024 = 8 x (64 c x 2 jt)
  const int c = xcd * 64 + (i2 >> 1), jt = i2 & 1;
  const size_t cb = (size_t)c * 65536;
  const int t = threadIdx.x, lane = t & 63, wid = t >> 6;
  const int wr = wid >> 1, wc = wid & 1, lr = lane & 15, lq = lane >> 4;

  const int arow0 = t >> 2, arow1 = 128 + (t >> 2);
  const int aks0 = (((t & 3) ^ ((arow0 >> 1) & 3)) << 3);
  const int aks1 = (((t & 3) ^ ((arow1 >> 1) & 3)) << 3);
  const int brow = t >> 2;
  const int bks  = (((t & 3) ^ ((brow >> 1) & 3)) << 3);

  int offA[4], offB[4];
#pragma unroll
  for (int mi = 0; mi < 4; ++mi) {
    const int rowA = wr * 64 + mi * 16 + lr;
    offA[mi] = rowA * 32 + ((lq ^ ((rowA >> 1) & 3)) << 3);
  }
#pragma unroll
  for (int ni = 0; ni < 4; ++ni) {
    const int rowB = wc * 64 + ni * 16 + lr;
    offB[ni] = rowB * 32 + ((lq ^ ((rowB >> 1) & 3)) << 3);
  }

  f32x4 acc[4][4] = {};

  for (int k0 = 0; k0 < 256; k0 += 32) {
    gload16(fb + cb + (size_t)arow0 * 256 + k0 + aks0, (char*)sA + t * 16);
    gload16(fb + cb + (size_t)arow1 * 256 + k0 + aks1, (char*)sA + 8192 + t * 16);
    gload16(gTb + cb + (size_t)(jt * 128 + brow) * 256 + k0 + bks, (char*)sB + t * 16);
    __syncthreads();
    half8 a[4], b[4];
#pragma unroll
    for (int mi = 0; mi < 4; ++mi) a[mi] = *(const half8*)(sA + offA[mi]);
#pragma unroll
    for (int ni = 0; ni < 4; ++ni) b[ni] = *(const half8*)(sB + offB[ni]);
#pragma unroll
    for (int mi = 0; mi < 4; ++mi)
#pragma unroll
      for (int ni = 0; ni < 4; ++ni)
        acc[mi][ni] = MFMAH(a[mi], b[ni], acc[mi][ni], 0, 0, 0);
    __syncthreads();
  }

  // ---- full-column softmax over i (rows span wr,mi,lq,r), per column
#pragma unroll
  for (int ni = 0; ni < 4; ++ni) {
    const int col = wc * 64 + ni * 16 + lr;
    float m = -3.4e38f;
#pragma unroll
    for (int mi = 0; mi < 4; ++mi) {
      f32x4 a = acc[mi][ni];
      m = fmaxf(m, fmaxf(fmaxf(a[0], a[1]), fmaxf(a[2], a[3])));
    }
    m = fmaxf(m, __shfl_xor(m, 16));
    m = fmaxf(m, __shfl_xor(m, 32));
    cmax[wr * 128 + col] = m;
  }
  __syncthreads();
#pragma unroll
  for (int ni = 0; ni < 4; ++ni) {
    const int col = wc * 64 + ni * 16 + lr;
    const float M = fmaxf(fmaxf(cmax[col], cmax[128 + col]),
                          fmaxf(cmax[256 + col], cmax[384 + col]));
    float s = 0.f;
#pragma unroll
    for (int mi = 0; mi < 4; ++mi)
#pragma unroll
      for (int r = 0; r < 4; ++r) {
        float e = __expf(acc[mi][ni][r] - M);
        acc[mi][ni][r] = e; s += e;
      }
    s += __shfl_xor(s, 16);
    s += __shfl_xor(s, 32);
    csum[wr * 128 + col] = s;
  }
  __syncthreads();
#pragma unroll
  for (int ni = 0; ni < 4; ++ni) {
    const int col = wc * 64 + ni * 16 + lr;
    const float rs = 1.f / (csum[col] + csum[128 + col] + csum[256 + col] + csum[384 + col]);
    const int j = jt * 128 + col;
#pragma unroll
    for (int mi = 0; mi < 4; ++mi) {
      u16x4 w = { f2h(acc[mi][ni][0] * rs), f2h(acc[mi][ni][1] * rs),
                  f2h(acc[mi][ni][2] * rs), f2h(acc[mi][ni][3] * rs) };
      *(u16x4*)(Pt + cb + (size_t)j * 256 + wr * 64 + mi * 16 + lq * 4) = w;
    }
  }
}

// ---------------------------------------------------------------------------
// attn: out[c,i,j] = x[c,i,j] + sum_k h[c,i,k] * PT[c,j,k]. fp16 MFMA.
// ---------------------------------------------------------------------------
__global__ __launch_bounds__(256)
void attn_kernel(const u16* __restrict__ hb, const u16* __restrict__ Pt,
                 const float* __restrict__ x, float* __restrict__ out)
{
  __shared__ u16 sA[128 * 32], sB[128 * 32];
  const int bid = blockIdx.x;
  const int wg = (bid & 7) * 256 + (bid >> 3);
  const int c = wg >> 2, tm = (wg >> 1) & 1, tn = wg & 1;
  const int t = threadIdx.x, lane = t & 63, wid = t >> 6;
  const int wr = wid >> 1, wc = wid & 1, lr = lane & 15, lq = lane >> 4;
  const size_t cb = (size_t)c * 65536;
  const int grl = t >> 2, gko = t & 3;
  const int ldsb = wid * 1024;

  f32x4 acc[4][4] = {};

  for (int k0 = 0; k0 < 256; k0 += 32) {
#pragma unroll
    for (int q = 0; q < 2; ++q) {
      const int row = q * 64 + grl;
      gload16(hb + cb + (size_t)(tm * 128 + row) * 256 + k0 + gko * 8,
              (char*)sA + q * 4096 + ldsb);
      gload16(Pt + cb + (size_t)(tn * 128 + row) * 256 + k0 + gko * 8,
              (char*)sB + q * 4096 + ldsb);
    }
    __syncthreads();
    half8 af[4], bfr[4];
#pragma unroll
    for (int mi = 0; mi < 4; ++mi)
      af[mi] = *(const half8*)(sA + (wr * 64 + mi * 16 + lr) * 32 + lq * 8);
#pragma unroll
    for (int ni = 0; ni < 4; ++ni)
      bfr[ni] = *(const half8*)(sB + (wc * 64 + ni * 16 + lr) * 32 + lq * 8);
#pragma unroll
    for (int mi = 0; mi < 4; ++mi)
#pragma unroll
      for (int ni = 0; ni < 4; ++ni)
        acc[mi][ni] = MFMAH(af[mi], bfr[ni], acc[mi][ni], 0, 0, 0);
    __syncthreads();
  }

  const float* Xc = x + cb;
  float* Oc = out + cb;
  const int rb = tm * 128 + wr * 64, cbase = tn * 128 + wc * 64;
#pragma unroll
  for (int mi = 0; mi < 4; ++mi)
#pragma unroll
    for (int ni = 0; ni < 4; ++ni) {
      const int r0 = rb + mi * 16 + lq * 4, cc = cbase + ni * 16 + lr;
#pragma unroll
      for (int r = 0; r < 4; ++r) {
        const size_t idx = (size_t)(r0 + r) * 256 + cc;
        Oc[idx] = Xc[idx] + acc[mi][ni][r];
      }
    }
}

// ---------------------------------------------------------------------------
extern "C" void kernel_launch(void* const* d_in, const int* in_sizes, int n_in,
                              void* d_out, int out_size, void* d_ws, size_t ws_size,
                              hipStream_t stream)
{
  (void)in_sizes; (void)n_in; (void)out_size; (void)ws_size;
  const float* x  = (const float*)d_in[0];
  const float* Wf = (const float*)d_in[1];
  const float* Wg = (const float*)d_in[2];
  const float* Wh = (const float*)d_in[3];
  float* out = (float*)d_out;
  char*  ws  = (char*)d_ws;

  // ws: [x16 64Mi][gT16 64Mi][h16 64Mi]; f16 lives in d_out's first 64 MiB.
  u16* x16  = (u16*)ws;
  u16* gT16 = (u16*)(ws + 67108864);
  u16* h16  = (u16*)(ws + 134217728);
  u16* f16  = (u16*)d_out;
  u16* Pt   = x16;   // PT overwrites x16 after conv_fgh

  dim3 blk(256, 1, 1);
  prep_w       <<<dim3(1536, 1, 1), blk, 0, stream>>>(Wf, Wg, Wh);
  prep_x       <<<dim3(2048, 1, 1), blk, 0, stream>>>(x, x16);
  conv_fgh     <<<dim3(6144, 1, 1), blk, 0, stream>>>(x16, f16, gT16, h16);
  scores_kernel<<<dim3(1024, 1, 1), dim3(512, 1, 1), 0, stream>>>(f16, gT16, Pt);
  attn_kernel  <<<dim3(2048, 1, 1), blk, 0, stream>>>(h16, Pt, x, out);
}

// Round 11
// 354.798 us; speedup vs baseline: 1.9039x; 1.1679x over previous
//
#include <hip/hip_runtime.h>

typedef unsigned short u16;
typedef unsigned int   u32;
typedef __attribute__((ext_vector_type(8))) _Float16 half8;
typedef __attribute__((ext_vector_type(4))) float f32x4;
typedef __attribute__((ext_vector_type(2))) float f32x2;
typedef __attribute__((ext_vector_type(4))) u32   u32x4;
typedef __attribute__((ext_vector_type(4))) unsigned short u16x4;

#define MFMAH __builtin_amdgcn_mfma_f32_16x16x32_f16

// W fp16 storage: rows 0-511 = Wf, 512-1023 = Wg, 1024-1535 = Wh, k-contig.
__device__ u16 W16[786432];

__device__ __forceinline__ u16 f2h(float f) {            // fp32 -> fp16 rne
  _Float16 h = (_Float16)f;
  union { _Float16 hh; u16 u; } cv; cv.hh = h; return cv.u;
}
__device__ __forceinline__ u32 pkh(float a, float b) {   // two rne halves packed
  return (u32)f2h(a) | ((u32)f2h(b) << 16);
}
__device__ __forceinline__ void gload16(const void* g, void* l) {
  __builtin_amdgcn_global_load_lds(
      (const __attribute__((address_space(1))) void*)g,
      (__attribute__((address_space(3))) void*)l, 16, 0, 0);
}

// ---------------------------------------------------------------------------
// prep_w: W fp32 -> fp16 (rne)
// ---------------------------------------------------------------------------
__global__ __launch_bounds__(256)
void prep_w(const float* __restrict__ Wf, const float* __restrict__ Wg,
            const float* __restrict__ Wh)
{
  const int r = blockIdx.x;                    // 0..1535
  const int k = threadIdx.x * 2;
  const float* src = (r < 512) ? (Wf + (size_t)r * 512)
                   : (r < 1024) ? (Wg + (size_t)(r - 512) * 512)
                                : (Wh + (size_t)(r - 1024) * 512);
  f32x2 v = *(const f32x2*)(src + k);
  *(u32*)(W16 + (size_t)r * 512 + k) = pkh(v[0], v[1]);
}

// ---------------------------------------------------------------------------
// prep_x: x[512][65536] fp32 -> xT[65536][512] fp16 (rne).
// ---------------------------------------------------------------------------
__global__ __launch_bounds__(256)
void prep_x(const float* __restrict__ x, u16* __restrict__ x16)
{
  __shared__ float tile[64 * 256];             // 64 KB
  const int bk = blockIdx.x & 7, bn = blockIdx.x >> 3;
  const int t = threadIdx.x;
  const int cw = (t & 63) * 4, r0 = (t >> 6) * 16;
#pragma unroll
  for (int it = 0; it < 16; ++it) {
    const int r = r0 + it;
    *(f32x4*)&tile[r * 256 + cw] =
        *(const f32x4*)(x + (size_t)(bk * 64 + r) * 65536 + (size_t)bn * 256 + cw);
  }
  __syncthreads();
  u32 w[32];
#pragma unroll
  for (int q = 0; q < 32; ++q)
    w[q] = pkh(tile[(2 * q) * 256 + t], tile[(2 * q + 1) * 256 + t]);
  const size_t ob = (size_t)(bn * 256 + t) * 512 + bk * 64;
#pragma unroll
  for (int c4 = 0; c4 < 8; ++c4)
    *(u32x4*)(x16 + ob + c4 * 8) = (u32x4){w[4*c4], w[4*c4+1], w[4*c4+2], w[4*c4+3]};
}

// ---------------------------------------------------------------------------
// conv_fgh: fused fp16 GEMM, M=1536 ([f;g;h] = [Wf;Wg;Wh] @ x).
// BM=256 x BN=128, BK=32, 512 thr = 8 waves (4M x 2N), per-wave 64x64.
// tm2 0-1: f, 2-3: g (sigma B rows -> writes gT), 4-5: h.
// Staging: A 2 gloads + B 1 gload per thread per K-step, k-slot swizzle.
// XCD-chunked stripe-inner grid: 6 tm2 share each B-tile on one XCD.
// ---------------------------------------------------------------------------
__global__ __launch_bounds__(512, 4)
void conv_fgh(const u16* __restrict__ x16, u16* __restrict__ fb,
              u16* __restrict__ gTb, u16* __restrict__ hb)
{
  __shared__ u16 sA[8192], sB[4096];           // 16 KB + 8 KB
  const int bid = blockIdx.x;
  const int xcd = bid & 7, idx = bid >> 3;     // 3072 = 8 XCD x (64 tn x 6 tm2)
  const int tn = xcd * 64 + idx / 6;
  const int tm2 = idx % 6;
  const bool gmode = (tm2 >= 2) && (tm2 < 4);
  const int t = threadIdx.x, lane = t & 63, wid = t >> 6;
  const int wr = wid >> 1, wc = wid & 1, lr = lane & 15, lq = lane >> 4;

  // A chunks: e = q*512+t -> row = e>>2 (0..255), slot = e&3
  const int ar0 = t >> 2, ar1 = 128 + (t >> 2);
  const int aks0 = (((t & 3) ^ ((ar0 >> 1) & 3)) << 3);
  const int aks1 = (((t & 3) ^ ((ar1 >> 1) & 3)) << 3);
  const int garA0 = tm2 * 256 + ar0, garA1 = tm2 * 256 + ar1;
  // B chunk: e = t -> row = t>>2 (0..127)
  const int br = t >> 2;
  const int bks = (((t & 3) ^ ((br >> 1) & 3)) << 3);
  const int bxr = gmode ? ((((tn & 1) << 7) + br) * 256 + (tn >> 1)) : (tn * 128 + br);

  int offA[4], offB[4];
#pragma unroll
  for (int mi = 0; mi < 4; ++mi) {
    const int rowA = wr * 64 + mi * 16 + lr;   // 0..255
    offA[mi] = rowA * 32 + ((lq ^ ((rowA >> 1) & 3)) << 3);
  }
#pragma unroll
  for (int ni = 0; ni < 4; ++ni) {
    const int rowB = wc * 64 + ni * 16 + lr;   // 0..127
    offB[ni] = rowB * 32 + ((lq ^ ((rowB >> 1) & 3)) << 3);
  }

  f32x4 acc[4][4] = {};

  for (int k0 = 0; k0 < 512; k0 += 32) {
    gload16(W16 + (size_t)garA0 * 512 + k0 + aks0, (char*)sA + t * 16);
    gload16(W16 + (size_t)garA1 * 512 + k0 + aks1, (char*)sA + 8192 + t * 16);
    gload16(x16 + (size_t)bxr * 512 + k0 + bks,    (char*)sB + t * 16);
    __syncthreads();
    half8 a[4], b[4];
#pragma unroll
    for (int mi = 0; mi < 4; ++mi) a[mi] = *(const half8*)(sA + offA[mi]);
#pragma unroll
    for (int ni = 0; ni < 4; ++ni) b[ni] = *(const half8*)(sB + offB[ni]);
#pragma unroll
    for (int mi = 0; mi < 4; ++mi)
#pragma unroll
      for (int ni = 0; ni < 4; ++ni)
        acc[mi][ni] = MFMAH(a[mi], b[ni], acc[mi][ni], 0, 0, 0);
    __syncthreads();
  }

  const int cls = tm2 >> 1;
  u16* dst = (cls == 0) ? fb : (cls == 1) ? gTb : hb;
  const int rbase = (tm2 & 1) * 256 + wr * 64;
  const int cbase = tn * 128 + wc * 64;
#pragma unroll
  for (int mi = 0; mi < 4; ++mi)
#pragma unroll
    for (int ni = 0; ni < 4; ++ni) {
      const int r0 = rbase + mi * 16 + lq * 4;
      const int cc = cbase + ni * 16 + lr;
#pragma unroll
      for (int r = 0; r < 4; ++r)
        dst[(size_t)(r0 + r) * 65536 + cc] = f2h(acc[mi][ni][r]);
    }
}

// ---------------------------------------------------------------------------
// scores: per (c, jt): S = f[c](256 x 256) @ gT[c][jt](128 x 256)^T, fp16.
// Block owns FULL softmax columns -> writes normalized PT[c][j][i] fp16.
// ---------------------------------------------------------------------------
__global__ __launch_bounds__(512)
void scores_kernel(const u16* __restrict__ fb, const u16* __restrict__ gTb,
                   u16* __restrict__ Pt)
{
  __shared__ u16 sA[8192];                     // 16 KB: 256 rows x 32 k
  __shared__ u16 sB[4096];                     // 8 KB: 128 rows x 32 k
  __shared__ float cmax[512], csum[512];
  const int bid = blockIdx.x;
  const int xcd = bid & 7, i2 = bid >> 3;      // 1024 = 8 x (64 c x 2 jt)
  const int c = xcd * 64 + (i2 >> 1), jt = i2 & 1;
  const size_t cb = (size_t)c * 65536;
  const int t = threadIdx.x, lane = t & 63, wid = t >> 6;
  const int wr = wid >> 1, wc = wid & 1, lr = lane & 15, lq = lane >> 4;

  const int arow0 = t >> 2, arow1 = 128 + (t >> 2);
  const int aks0 = (((t & 3) ^ ((arow0 >> 1) & 3)) << 3);
  const int aks1 = (((t & 3) ^ ((arow1 >> 1) & 3)) << 3);
  const int brow = t >> 2;
  const int bks  = (((t & 3) ^ ((brow >> 1) & 3)) << 3);

  int offA[4], offB[4];
#pragma unroll
  for (int mi = 0; mi < 4; ++mi) {
    const int rowA = wr * 64 + mi * 16 + lr;
    offA[mi] = rowA * 32 + ((lq ^ ((rowA >> 1) & 3)) << 3);
  }
#pragma unroll
  for (int ni = 0; ni < 4; ++ni) {
    const int rowB = wc * 64 + ni * 16 + lr;
    offB[ni] = rowB * 32 + ((lq ^ ((rowB >> 1) & 3)) << 3);
  }

  f32x4 acc[4][4] = {};

  for (int k0 = 0; k0 < 256; k0 += 32) {
    gload16(fb + cb + (size_t)arow0 * 256 + k0 + aks0, (char*)sA + t * 16);
    gload16(fb + cb + (size_t)arow1 * 256 + k0 + aks1, (char*)sA + 8192 + t * 16);
    gload16(gTb + cb + (size_t)(jt * 128 + brow) * 256 + k0 + bks, (char*)sB + t * 16);
    __syncthreads();
    half8 a[4], b[4];
#pragma unroll
    for (int mi = 0; mi < 4; ++mi) a[mi] = *(const half8*)(sA + offA[mi]);
#pragma unroll
    for (int ni = 0; ni < 4; ++ni) b[ni] = *(const half8*)(sB + offB[ni]);
#pragma unroll
    for (int mi = 0; mi < 4; ++mi)
#pragma unroll
      for (int ni = 0; ni < 4; ++ni)
        acc[mi][ni] = MFMAH(a[mi], b[ni], acc[mi][ni], 0, 0, 0);
    __syncthreads();
  }

  // ---- full-column softmax over i (rows span wr,mi,lq,r), per column
#pragma unroll
  for (int ni = 0; ni < 4; ++ni) {
    const int col = wc * 64 + ni * 16 + lr;
    float m = -3.4e38f;
#pragma unroll
    for (int mi = 0; mi < 4; ++mi) {
      f32x4 a = acc[mi][ni];
      m = fmaxf(m, fmaxf(fmaxf(a[0], a[1]), fmaxf(a[2], a[3])));
    }
    m = fmaxf(m, __shfl_xor(m, 16));
    m = fmaxf(m, __shfl_xor(m, 32));
    cmax[wr * 128 + col] = m;
  }
  __syncthreads();
#pragma unroll
  for (int ni = 0; ni < 4; ++ni) {
    const int col = wc * 64 + ni * 16 + lr;
    const float M = fmaxf(fmaxf(cmax[col], cmax[128 + col]),
                          fmaxf(cmax[256 + col], cmax[384 + col]));
    float s = 0.f;
#pragma unroll
    for (int mi = 0; mi < 4; ++mi)
#pragma unroll
      for (int r = 0; r < 4; ++r) {
        float e = __expf(acc[mi][ni][r] - M);
        acc[mi][ni][r] = e; s += e;
      }
    s += __shfl_xor(s, 16);
    s += __shfl_xor(s, 32);
    csum[wr * 128 + col] = s;
  }
  __syncthreads();
#pragma unroll
  for (int ni = 0; ni < 4; ++ni) {
    const int col = wc * 64 + ni * 16 + lr;
    const float rs = 1.f / (csum[col] + csum[128 + col] + csum[256 + col] + csum[384 + col]);
    const int j = jt * 128 + col;
#pragma unroll
    for (int mi = 0; mi < 4; ++mi) {
      u16x4 w = { f2h(acc[mi][ni][0] * rs), f2h(acc[mi][ni][1] * rs),
                  f2h(acc[mi][ni][2] * rs), f2h(acc[mi][ni][3] * rs) };
      *(u16x4*)(Pt + cb + (size_t)j * 256 + wr * 64 + mi * 16 + lq * 4) = w;
    }
  }
}

// ---------------------------------------------------------------------------
// attn: out[c,a,j] = x[c,a,j] + sum_i h[c,a,i] * PT[c,j,i]. fp16 MFMA.
// 256x128 tile (2 blocks/channel), 512 thr = 8 waves (4M x 2N) -> h read
// once per block, Pt-half once; 3 gloads/thread/K-step.
// ---------------------------------------------------------------------------
__global__ __launch_bounds__(512, 4)
void attn_kernel(const u16* __restrict__ hb, const u16* __restrict__ Pt,
                 const float* __restrict__ x, float* __restrict__ out)
{
  __shared__ u16 sA[8192], sB[4096];           // 16 KB + 8 KB
  const int bid = blockIdx.x;
  const int xcd = bid & 7, i2 = bid >> 3;      // 1024 = 8 x (64 c x 2 tn)
  const int c = xcd * 64 + (i2 >> 1), tn = i2 & 1;
  const size_t cb = (size_t)c * 65536;
  const int t = threadIdx.x, lane = t & 63, wid = t >> 6;
  const int wr = wid >> 1, wc = wid & 1, lr = lane & 15, lq = lane >> 4;

  const int ar0 = t >> 2, ar1 = 128 + (t >> 2);
  const int aks0 = (((t & 3) ^ ((ar0 >> 1) & 3)) << 3);
  const int aks1 = (((t & 3) ^ ((ar1 >> 1) & 3)) << 3);
  const int br = t >> 2;
  const int bks = (((t & 3) ^ ((br >> 1) & 3)) << 3);

  int offA[4], offB[4];
#pragma unroll
  for (int mi = 0; mi < 4; ++mi) {
    const int rowA = wr * 64 + mi * 16 + lr;   // 0..255
    offA[mi] = rowA * 32 + ((lq ^ ((rowA >> 1) & 3)) << 3);
  }
#pragma unroll
  for (int ni = 0; ni < 4; ++ni) {
    const int rowB = wc * 64 + ni * 16 + lr;   // 0..127
    offB[ni] = rowB * 32 + ((lq ^ ((rowB >> 1) & 3)) << 3);
  }

  f32x4 acc[4][4] = {};

  for (int k0 = 0; k0 < 256; k0 += 32) {
    gload16(hb + cb + (size_t)ar0 * 256 + k0 + aks0, (char*)sA + t * 16);
    gload16(hb + cb + (size_t)ar1 * 256 + k0 + aks1, (char*)sA + 8192 + t * 16);
    gload16(Pt + cb + (size_t)(tn * 128 + br) * 256 + k0 + bks, (char*)sB + t * 16);
    __syncthreads();
    half8 a[4], b[4];
#pragma unroll
    for (int mi = 0; mi < 4; ++mi) a[mi] = *(const half8*)(sA + offA[mi]);
#pragma unroll
    for (int ni = 0; ni < 4; ++ni) b[ni] = *(const half8*)(sB + offB[ni]);
#pragma unroll
    for (int mi = 0; mi < 4; ++mi)
#pragma unroll
      for (int ni = 0; ni < 4; ++ni)
        acc[mi][ni] = MFMAH(a[mi], b[ni], acc[mi][ni], 0, 0, 0);
    __syncthreads();
  }

  const float* Xc = x + cb;
  float* Oc = out + cb;
  const int rbase = wr * 64;                   // rows 0..255
  const int cbase = tn * 128 + wc * 64;        // cols 0..255
#pragma unroll
  for (int mi = 0; mi < 4; ++mi)
#pragma unroll
    for (int ni = 0; ni < 4; ++ni) {
      const int r0 = rbase + mi * 16 + lq * 4, cc = cbase + ni * 16 + lr;
#pragma unroll
      for (int r = 0; r < 4; ++r) {
        const size_t idx = (size_t)(r0 + r) * 256 + cc;
        Oc[idx] = Xc[idx] + acc[mi][ni][r];
      }
    }
}

// ---------------------------------------------------------------------------
extern "C" void kernel_launch(void* const* d_in, const int* in_sizes, int n_in,
                              void* d_out, int out_size, void* d_ws, size_t ws_size,
                              hipStream_t stream)
{
  (void)in_sizes; (void)n_in; (void)out_size; (void)ws_size;
  const float* x  = (const float*)d_in[0];
  const float* Wf = (const float*)d_in[1];
  const float* Wg = (const float*)d_in[2];
  const float* Wh = (const float*)d_in[3];
  float* out = (float*)d_out;
  char*  ws  = (char*)d_ws;

  // ws: [x16 64Mi][gT16 64Mi][h16 64Mi]; f16 lives in d_out's first 64 MiB.
  u16* x16  = (u16*)ws;
  u16* gT16 = (u16*)(ws + 67108864);
  u16* h16  = (u16*)(ws + 134217728);
  u16* f16  = (u16*)d_out;
  u16* Pt   = x16;   // PT overwrites x16 after conv_fgh

  dim3 blk(256, 1, 1);
  prep_w       <<<dim3(1536, 1, 1), blk, 0, stream>>>(Wf, Wg, Wh);
  prep_x       <<<dim3(2048, 1, 1), blk, 0, stream>>>(x, x16);
  conv_fgh     <<<dim3(3072, 1, 1), dim3(512, 1, 1), 0, stream>>>(x16, f16, gT16, h16);
  scores_kernel<<<dim3(1024, 1, 1), dim3(512, 1, 1), 0, stream>>>(f16, gT16, Pt);
  attn_kernel  <<<dim3(1024, 1, 1), dim3(512, 1, 1), 0, stream>>>(h16, Pt, x, out);
}